// Round 1
// baseline (6281.429 us; speedup 1.0000x reference)
//
#include <hip/hip_runtime.h>

// EA-LSTM fused kernel.
// B=256 blocks, one batch element per block (1 block/CU on 256 CUs).
// 768 threads = 12 waves. Thread (a,kq), t = kq*192 + a:
//   owns cols [4a..4a+3] x K-chunk [72*kq .. 72*kq+71] of the stacked
//   weight matrix [W_hh; W_ih] (288 x 768), held in 288 VGPRs for all 365 steps.
// Per step: broadcast-read stacked [h; x_t] (288 floats) from LDS, 288 FMAs,
// 4-way K-partial reduce via LDS, gate elementwise on threads 0..255,
// c-state resident in registers. fp32 throughout (no accuracy risk).

#define BB 256
#define SS 365
#define FD 32
#define FS 27
#define HH 256
#define G3 768           // 3*H
#define KTOT 288         // H + FD stacked K
#define KQ 4             // K split ways
#define KCH 72           // KTOT/KQ
#define NA 192           // column groups (G3/4)
#define PPITCH 776       // partials row pitch (768 + 8) to spread banks

__global__ __launch_bounds__(768) void ealstm_kernel(
    const float* __restrict__ x_d, const float* __restrict__ x_s,
    const float* __restrict__ W_ih, const float* __restrict__ W_hh,
    const float* __restrict__ W_sh, const float* __restrict__ bias,
    const float* __restrict__ bias_s, const float* __restrict__ W_fc,
    const float* __restrict__ b_fc, float* __restrict__ d_out)
{
    __shared__ __align__(16) float hbuf[KTOT];       // [h(256); x_t(32)]
    __shared__ __align__(16) float partials[KQ][PPITCH];
    __shared__ float outp[4];

    const int t = threadIdx.x;
    const int b = blockIdx.x;
    const int kq = t / NA;        // 0..3   (wave-uniform: 3 waves per kq)
    const int a  = t - kq * NA;   // 0..191
    const int col4 = 4 * a;

    // ---- load private weight tile: stacked rows kq*72..+71, cols col4..col4+3
    float4 w[KCH];
#pragma unroll
    for (int i = 0; i < KCH; ++i) {
        const int k = kq * KCH + i;
        const float* src = (k < HH) ? (W_hh + (size_t)k * G3 + col4)
                                    : (W_ih + (size_t)(k - HH) * G3 + col4);
        w[i] = *reinterpret_cast<const float4*>(src);
    }

    // ---- elementwise-lane state (threads 0..255)
    float c_state = 0.f, ig = 0.f, bf = 0.f, bo = 0.f, bg = 0.f, wfc = 0.f;
    if (t < HH) {
        float accs = bias_s[t];
        for (int k = 0; k < FS; ++k)
            accs = fmaf(x_s[(size_t)b * FS + k], W_sh[(size_t)k * HH + t], accs);
        ig = 1.f / (1.f + __expf(-accs));     // static input gate
        bf = bias[t]; bo = bias[t + HH]; bg = bias[t + 2 * HH];
        wfc = W_fc[t];
        hbuf[t] = 0.f;                         // h0 = 0
    }
    // stage x_t for s=0
    if (t >= 512 && t < 512 + FD) {
        hbuf[HH + (t - 512)] = x_d[(size_t)b * SS * FD + (t - 512)];
    }
    const float bfc = b_fc[0];
    __syncthreads();

    float* __restrict__ out_fc = d_out;                        // [B,S,1]
    float* __restrict__ hn_out = d_out + (size_t)BB * SS;      // [B,S,H]
    float* __restrict__ cn_out = hn_out + (size_t)BB * SS * HH;

    for (int s = 0; s < SS; ++s) {
        // ---- partial GEMV: acc[c] = sum_{k in chunk} hbuf[k] * W[k][col4+c]
        float4 acc = make_float4(0.f, 0.f, 0.f, 0.f);
        const float4* hv4 = reinterpret_cast<const float4*>(hbuf + kq * KCH);
#pragma unroll
        for (int i = 0; i < KCH / 4; ++i) {
            const float4 hv = hv4[i];                    // ds_read_b128, wave-uniform broadcast
            acc.x = fmaf(hv.x, w[4 * i + 0].x, acc.x);
            acc.y = fmaf(hv.x, w[4 * i + 0].y, acc.y);
            acc.z = fmaf(hv.x, w[4 * i + 0].z, acc.z);
            acc.w = fmaf(hv.x, w[4 * i + 0].w, acc.w);
            acc.x = fmaf(hv.y, w[4 * i + 1].x, acc.x);
            acc.y = fmaf(hv.y, w[4 * i + 1].y, acc.y);
            acc.z = fmaf(hv.y, w[4 * i + 1].z, acc.z);
            acc.w = fmaf(hv.y, w[4 * i + 1].w, acc.w);
            acc.x = fmaf(hv.z, w[4 * i + 2].x, acc.x);
            acc.y = fmaf(hv.z, w[4 * i + 2].y, acc.y);
            acc.z = fmaf(hv.z, w[4 * i + 2].z, acc.z);
            acc.w = fmaf(hv.z, w[4 * i + 2].w, acc.w);
            acc.x = fmaf(hv.w, w[4 * i + 3].x, acc.x);
            acc.y = fmaf(hv.w, w[4 * i + 3].y, acc.y);
            acc.z = fmaf(hv.w, w[4 * i + 3].z, acc.z);
            acc.w = fmaf(hv.w, w[4 * i + 3].w, acc.w);
        }
        *reinterpret_cast<float4*>(&partials[kq][col4]) = acc;
        __syncthreads();

        if (t < HH) {
            // gates = sum of 4 K-partials + bias (+ x_t@W_ih folded in via stacking)
            float f = partials[0][t] + partials[1][t] + partials[2][t] + partials[3][t] + bf;
            float o = partials[0][t + HH] + partials[1][t + HH] + partials[2][t + HH] + partials[3][t + HH] + bo;
            float g = partials[0][t + 2 * HH] + partials[1][t + 2 * HH] + partials[2][t + 2 * HH] + partials[3][t + 2 * HH] + bg;
            const float sf = 1.f / (1.f + __expf(-f));
            const float so = 1.f / (1.f + __expf(-o));
            const float tg = 1.f - 2.f / (1.f + __expf(2.f * g));   // overflow-safe tanh
            c_state = sf * c_state + ig * tg;
            const float tc = 1.f - 2.f / (1.f + __expf(2.f * c_state));
            const float h1 = so * tc;
            hbuf[t] = h1;
            const size_t oidx = ((size_t)b * SS + s) * HH + t;
            hn_out[oidx] = h1;
            cn_out[oidx] = c_state;
            // fc head: p = h1 * W_fc[t], reduce 64-lane waves
            float p = h1 * wfc;
            for (int d = 32; d > 0; d >>= 1) p += __shfl_down(p, d);
            if ((t & 63) == 0) outp[t >> 6] = p;
        } else if (t >= 512 && t < 512 + FD) {
            // stage next step's x_t while elementwise lanes work
            const int sn = (s + 1 < SS) ? (s + 1) : s;
            hbuf[HH + (t - 512)] = x_d[(size_t)b * SS * FD + (size_t)sn * FD + (t - 512)];
        }
        __syncthreads();
        if (t == 0) {
            out_fc[(size_t)b * SS + s] = outp[0] + outp[1] + outp[2] + outp[3] + bfc;
        }
    }
}

extern "C" void kernel_launch(void* const* d_in, const int* in_sizes, int n_in,
                              void* d_out, int out_size, void* d_ws, size_t ws_size,
                              hipStream_t stream) {
    const float* x_d    = (const float*)d_in[0];
    const float* x_s    = (const float*)d_in[1];
    const float* W_ih   = (const float*)d_in[2];
    const float* W_hh   = (const float*)d_in[3];
    const float* W_sh   = (const float*)d_in[4];
    const float* bias   = (const float*)d_in[5];
    const float* bias_s = (const float*)d_in[6];
    const float* W_fc   = (const float*)d_in[7];
    const float* b_fc   = (const float*)d_in[8];

    ealstm_kernel<<<dim3(BB), dim3(768), 0, stream>>>(
        x_d, x_s, W_ih, W_hh, W_sh, bias, bias_s, W_fc, b_fc, (float*)d_out);
}